// Round 17
// baseline (39.105 us; speedup 1.0000x reference)
//
#include <hip/hip_runtime.h>
#include <cstdint>
#include <cmath>

#define NN   4096
#define DXX  128
#define DD   64
#define KK   256
#define HH   256
#define DIN  192
#define ROWS 8
#define NT   512
#define GRID (NN/ROWS)   // 512 blocks, 2 per CU (8 waves each) -> 4 waves/SIMD, async blocks

typedef __attribute__((ext_vector_type(8))) short short8;
typedef __attribute__((ext_vector_type(4))) float f32x4;
#define MFMA __builtin_amdgcn_mfma_f32_16x16x32_bf16

// ---- packed-weight offsets in d_ws (ushort units) ----
#define OW1 0          // 3 terms x 16ct x 6ks x 512
#define OW2 147456     // 3 x 16 x 8 x 512
#define OW3 344064     // 3 x 4  x 8 x 512
#define OCT 393216     // 3 x 16 x 2 x 512
#define OCN 442368     // 256 f32 (codebook row norms)

// ---- LDS strides ----
#define SW  264        // act row stride (ushorts)
#define SG  72         // gt-split row stride (ushorts)
#define SSP 260        // score row stride (floats)
#define SSG 68         // sgt row stride (floats)

__device__ __forceinline__ unsigned short f2bf(float x){
  uint32_t u = __float_as_uint(x);
  return (unsigned short)((u + 0x7fffu + ((u>>16)&1u)) >> 16);
}
__device__ __forceinline__ float bf2f(unsigned short b){
  return __uint_as_float(((uint32_t)b)<<16);
}
__device__ __forceinline__ void split3(float x, unsigned short& h, unsigned short& m, unsigned short& l){
  h = f2bf(x); float r1 = x - bf2f(h);
  m = f2bf(r1); float r2 = r1 - bf2f(m);
  l = f2bf(r2);
}

// ---------------- Threefry-2x32 (20 rounds), exact JAX semantics ----------------
__device__ __forceinline__ uint32_t rotl32(uint32_t v, uint32_t r){ return (v<<r)|(v>>(32u-r)); }
__device__ __forceinline__ void tf2x32(uint32_t k0, uint32_t k1,
                                       uint32_t x0, uint32_t x1,
                                       uint32_t& o0, uint32_t& o1){
  const uint32_t ks0=k0, ks1=k1, ks2 = k0 ^ k1 ^ 0x1BD11BDAu;
  x0 += ks0; x1 += ks1;
  x0+=x1; x1=rotl32(x1,13); x1^=x0;
  x0+=x1; x1=rotl32(x1,15); x1^=x0;
  x0+=x1; x1=rotl32(x1,26); x1^=x0;
  x0+=x1; x1=rotl32(x1, 6); x1^=x0;
  x0+=ks1; x1+=ks2+1u;
  x0+=x1; x1=rotl32(x1,17); x1^=x0;
  x0+=x1; x1=rotl32(x1,29); x1^=x0;
  x0+=x1; x1=rotl32(x1,16); x1^=x0;
  x0+=x1; x1=rotl32(x1,24); x1^=x0;
  x0+=ks2; x1+=ks0+2u;
  x0+=x1; x1=rotl32(x1,13); x1^=x0;
  x0+=x1; x1=rotl32(x1,15); x1^=x0;
  x0+=x1; x1=rotl32(x1,26); x1^=x0;
  x0+=x1; x1=rotl32(x1, 6); x1^=x0;
  x0+=ks0; x1+=ks1+3u;
  x0+=x1; x1=rotl32(x1,17); x1^=x0;
  x0+=x1; x1=rotl32(x1,29); x1^=x0;
  x0+=x1; x1=rotl32(x1,16); x1^=x0;
  x0+=x1; x1=rotl32(x1,24); x1^=x0;
  x0+=ks1; x1+=ks2+4u;
  x0+=x1; x1=rotl32(x1,13); x1^=x0;
  x0+=x1; x1=rotl32(x1,15); x1^=x0;
  x0+=x1; x1=rotl32(x1,26); x1^=x0;
  x0+=x1; x1=rotl32(x1, 6); x1^=x0;
  x0+=ks2; x1+=ks0+5u;
  o0=x0; o1=x1;
}
__device__ __forceinline__ float gumbel_of(uint32_t ka0, uint32_t ka1, uint32_t idx){
  uint32_t o0,o1; tf2x32(ka0,ka1,0u,idx,o0,o1);
  const uint32_t bits = o0 ^ o1;
  const float TINY = 1.17549435e-38f;
  const float f = __uint_as_float((bits>>9) | 0x3F800000u) - 1.0f;
  const float u = fmaxf(TINY, f + TINY);
  return -logf(-logf(u));
}

// ---------------- prep v3: 73 fine blocks; coalesced -> LDS -> short8 ----------------
__global__ __launch_bounds__(256) void k_prep(const float* __restrict__ W1,
    const float* __restrict__ W2, const float* __restrict__ W3,
    const float* __restrict__ Cg, unsigned short* __restrict__ ws){
  const int b = blockIdx.x, t = threadIdx.x;
  __shared__ __align__(16) float lds[2112];
  if (b < 64){
    const float* W; int N, KS, NTt, ks, cg; size_t base;
    if (b < 24){ W=W1; N=256; KS=6; NTt=16; base=OW1; ks=b/4;      cg=b&3; }
    else if (b < 56){ W=W2; N=256; KS=8; NTt=16; base=OW2; ks=(b-24)/4; cg=(b-24)&3; }
    else { W=W3; N=64; KS=8; NTt=4; base=OW3; ks=b-56; cg=0; }
    const int k0 = ks*32, cb = cg*64;
    for (int idx=t; idx<512; idx+=256){
      int row = idx>>4, c4 = idx&15;
      float4 v = *(const float4*)&W[(size_t)(k0+row)*N + cb + c4*4];
      float* d = &lds[row*65 + c4*4];
      d[0]=v.x; d[1]=v.y; d[2]=v.z; d[3]=v.w;
    }
    __syncthreads();
    const size_t term = (size_t)NTt*KS*512;
    const int lane = t&63, ctl = t>>6;
    const int ct = cg*4 + ctl;
    const int cl = ctl*16 + (lane&15);
    const int kofs = 8*(lane>>4);
    short8 hv,mv,lv;
    #pragma unroll
    for (int j=0;j<8;++j){
      float w = lds[(kofs+j)*65 + cl];
      unsigned short h,m,lo; split3(w,h,m,lo);
      hv[j]=(short)h; mv[j]=(short)m; lv[j]=(short)lo;
    }
    const size_t o = base + ((size_t)ct*KS+ks)*512 + (size_t)lane*8;
    *(short8*)&ws[o]=hv; *(short8*)&ws[o+term]=mv; *(short8*)&ws[o+2*term]=lv;
  } else if (b < 72){
    const int ks = (b-64)/4, cg = (b-64)&3;
    const int d0 = ks*32, code0 = cg*64;
    for (int idx=t; idx<512; idx+=256){
      int code = idx>>3, d4 = idx&7;
      float4 v = *(const float4*)&Cg[(size_t)(code0+code)*64 + d0 + d4*4];
      float* d = &lds[code*33 + d4*4];
      d[0]=v.x; d[1]=v.y; d[2]=v.z; d[3]=v.w;
    }
    __syncthreads();
    const size_t term = (size_t)16*2*512;
    const int lane = t&63, ctl = t>>6;
    const int ct = cg*4 + ctl;
    const int cl = ctl*16 + (lane&15);
    const int kofs = 8*(lane>>4);
    short8 hv,mv,lv;
    #pragma unroll
    for (int j=0;j<8;++j){
      float w = lds[cl*33 + kofs + j];
      unsigned short h,m,lo; split3(w,h,m,lo);
      hv[j]=(short)h; mv[j]=(short)m; lv[j]=(short)lo;
    }
    const size_t o = OCT + ((size_t)ct*2+ks)*512 + (size_t)lane*8;
    *(short8*)&ws[o]=hv; *(short8*)&ws[o+term]=mv; *(short8*)&ws[o+2*term]=lv;
  } else {
    const int c = t;
    float s=0.f;
    #pragma unroll 8
    for (int d=0; d<64; ++d){ float v=Cg[(size_t)c*64+d]; s += v*v; }
    ((float*)(ws+OCN))[c] = s;
  }
}

// ---------------- fused main kernel: 8 waves, 2 ct/wave, 2 blocks/CU ----------------
__global__ __launch_bounds__(NT,4) void k_fused(
    const float* __restrict__ z, const float* __restrict__ ks,
    const float* __restrict__ xt, const void* __restrict__ maskp,
    const float* __restrict__ tr, const float* __restrict__ spk,
    const float* __restrict__ b1, const float* __restrict__ b2,
    const float* __restrict__ b3, const float* __restrict__ Cg,
    const int* __restrict__ seedp, const unsigned short* __restrict__ pws,
    float* __restrict__ out_z, float* __restrict__ out_kl,
    float* __restrict__ out_dkl, float* __restrict__ out_qk)
{
  const int t    = threadIdx.x;
  const int lane = t & 63;
  const int wv   = t >> 6;            // wave 0..7
  const int lr   = lane & 15;
  const int lg   = lane >> 4;
  const int n0   = blockIdx.x * ROWS;
  const int nw   = n0 + wv;           // finalize: wave wv owns row nw

  // LDS (bytes): A 3x8xSW ush [0,12672) | B 3x8xSW [12672,25344) (sp overlay)
  //              sgt 8xSSG f32 [25344,27520) | G 3x8xSG ush [27520,30976)
  __shared__ __align__(16) char smem[30976];
  unsigned short* Ah = (unsigned short*)smem;
  unsigned short* Am = Ah + 8*SW;
  unsigned short* Al = Am + 8*SW;
  unsigned short* Bh = (unsigned short*)(smem + 12672);
  unsigned short* Bm = Bh + 8*SW;
  unsigned short* Bl = Bm + 8*SW;
  float* sp  = (float*)(smem + 12672);
  float* sgt = (float*)(smem + 25344);
  unsigned short* Gh = (unsigned short*)(smem + 27520);
  unsigned short* Gm = Gh + 8*SG;
  unsigned short* Gl = Gm + 8*SG;
  __shared__ int sh_flag;
  const float* cnormp = (const float*)(pws + OCN);

  // ---- early long-latency loads (hidden under staging/MLP) ----
  const float4 ksq = ((const float4*)ks)[(size_t)nw*(KK/4)+lane];
  int kv=0x7fffffff;
  if (isfinite(ksq.x)&&ksq.x>0.5f) kv=4*lane+0;
  if (isfinite(ksq.y)&&ksq.y>0.5f&&4*lane+1<kv) kv=4*lane+1;
  if (isfinite(ksq.z)&&ksq.z>0.5f&&4*lane+2<kv) kv=4*lane+2;
  if (isfinite(ksq.w)&&ksq.w>0.5f&&4*lane+3<kv) kv=4*lane+3;
  { unsigned long long bl=__ballot(kv!=0x7fffffff);
    if (bl){ int src=(int)__builtin_ctzll(bl); kv=__shfl(kv,src,64); } else kv=0; }
  const int kidx = kv;
  const float4 trq = ((const float4*)tr)[(size_t)nw*(KK*KK/4)+(size_t)kidx*(KK/4)+lane];
  const unsigned char mb = ((const unsigned char*)maskp)[nw];
  const uint32_t      mw32 = ((const uint32_t*)maskp)[nw];

  if (t==0) sh_flag = 0;
  __syncthreads();
  {
    const uint32_t* mwp = (const uint32_t*)maskp;
    uint32_t bad=0;
    #pragma unroll
    for (int q=0;q<2;++q){ uint32_t wd=mwp[t+q*NT]; if (wd!=0u && wd!=1u && wd!=0x3F800000u) bad=1; }
    if (bad) atomicOr(&sh_flag,1);
  }

  // ---- stage layer-1 input with triple split ----
  for (int i=t; i<ROWS*DIN; i+=NT){
    int r=i/DIN, d=i%DIN; float v;
    if (d<DD){ v = z[(size_t)(n0+r)*DD+d]; if(!isfinite(v)) v=0.f; }
    else     { v = xt[(size_t)(n0+r)*DXX + (d-DD)]; }
    unsigned short h,m,l_; split3(v,h,m,l_);
    Ah[r*SW+d]=h; Am[r*SW+d]=m; Al[r*SW+d]=l_;
  }
  __syncthreads();
  const int flag = sh_flag;

  // ---- mfma GEMM layer: 2 ct/wave, A-tile = 8 rows (lr&7), store rows<8 ----
  auto gemm_layer = [&](const unsigned short* Xh, const unsigned short* Xm, const unsigned short* Xl,
                        int KS, size_t wbase, const float* bias,
                        unsigned short* Yh, unsigned short* Ym, unsigned short* Yl){
    const int ct0 = wv*2, ct1 = ct0+1;
    const size_t term = (size_t)16*KS*512;
    const float bb0 = bias[ct0*16+lr], bb1 = bias[ct1*16+lr];
    f32x4 a00 = {bb0,bb0,bb0,bb0}, a01 = {0.f,0.f,0.f,0.f};
    f32x4 a10 = {bb1,bb1,bb1,bb1}, a11 = {0.f,0.f,0.f,0.f};
    const int ar = (lr&7)*SW + lg*8;
    const unsigned short* p0 = &pws[wbase + ((size_t)ct0*KS)*512 + (size_t)lane*8];
    const unsigned short* p1 = &pws[wbase + ((size_t)ct1*KS)*512 + (size_t)lane*8];
    #pragma unroll 1
    for (int s=0; s<KS; ++s){
      const unsigned short* q0 = p0 + (size_t)s*512;
      const unsigned short* q1 = p1 + (size_t)s*512;
      short8 bh0=*(const short8*)q0, bm0=*(const short8*)(q0+term), bl0=*(const short8*)(q0+2*term);
      short8 bh1=*(const short8*)q1, bm1=*(const short8*)(q1+term), bl1=*(const short8*)(q1+2*term);
      short8 ah = *(const short8*)&Xh[ar + s*32];
      short8 am = *(const short8*)&Xm[ar + s*32];
      short8 al = *(const short8*)&Xl[ar + s*32];
      a00=MFMA(ah,bh0,a00,0,0,0); a01=MFMA(ah,bm0,a01,0,0,0);
      a00=MFMA(am,bh0,a00,0,0,0); a01=MFMA(am,bm0,a01,0,0,0);
      a00=MFMA(al,bh0,a00,0,0,0); a01=MFMA(ah,bl0,a01,0,0,0);
      a10=MFMA(ah,bh1,a10,0,0,0); a11=MFMA(ah,bm1,a11,0,0,0);
      a10=MFMA(am,bh1,a10,0,0,0); a11=MFMA(am,bm1,a11,0,0,0);
      a10=MFMA(al,bh1,a10,0,0,0); a11=MFMA(ah,bl1,a11,0,0,0);
    }
    if (lg < 2){
      #pragma unroll
      for (int j=0;j<4;++j){
        const int r = lg*4 + j;          // 0..7 valid
        float h0 = tanhf(a00[j]+a01[j]);
        unsigned short hh,hm,hl; split3(h0,hh,hm,hl);
        Yh[r*SW + ct0*16+lr]=hh; Ym[r*SW + ct0*16+lr]=hm; Yl[r*SW + ct0*16+lr]=hl;
        float h1v = tanhf(a10[j]+a11[j]);
        split3(h1v,hh,hm,hl);
        Yh[r*SW + ct1*16+lr]=hh; Ym[r*SW + ct1*16+lr]=hm; Yl[r*SW + ct1*16+lr]=hl;
      }
    }
  };

  gemm_layer(Ah,Am,Al, 6, OW1, b1, Bh,Bm,Bl);   // h1 -> bufB
  __syncthreads();
  gemm_layer(Bh,Bm,Bl, 8, OW2, b2, Ah,Am,Al);   // h2 -> bufA
  __syncthreads();

  // ---- MLP3: gt = h2 @ W3 + b3 (waves 0-3, one 16-col tile each) ----
  if (wv < 4){
    const int ct = wv;
    const size_t term = (size_t)4*8*512;
    const float bb = b3[ct*16+lr];
    f32x4 a0 = {bb,bb,bb,bb}, a1 = {0.f,0.f,0.f,0.f};
    const int ar = (lr&7)*SW + lg*8;
    const unsigned short* p = &pws[OW3 + ((size_t)ct*8)*512 + (size_t)lane*8];
    #pragma unroll 1
    for (int s=0; s<8; ++s){
      const unsigned short* q = p + (size_t)s*512;
      short8 bh=*(const short8*)q, bm=*(const short8*)(q+term), bl=*(const short8*)(q+2*term);
      short8 ah = *(const short8*)&Ah[ar + s*32];
      short8 am = *(const short8*)&Am[ar + s*32];
      short8 al = *(const short8*)&Al[ar + s*32];
      a0=MFMA(ah,bh,a0,0,0,0); a1=MFMA(ah,bm,a1,0,0,0);
      a0=MFMA(am,bh,a0,0,0,0); a1=MFMA(am,bm,a1,0,0,0);
      a0=MFMA(al,bh,a0,0,0,0); a1=MFMA(ah,bl,a1,0,0,0);
    }
    if (lg < 2){
      #pragma unroll
      for (int j=0;j<4;++j){
        const int r = lg*4 + j;
        float g = a0[j]+a1[j];
        sgt[r*SSG + ct*16+lr] = g;
        unsigned short gh,gm,gl; split3(g,gh,gm,gl);
        Gh[r*SG + ct*16+lr]=gh; Gm[r*SG + ct*16+lr]=gm; Gl[r*SG + ct*16+lr]=gl;
      }
    }
  }

  // ---- gumbel precompute (all waves, own row; overlaps MLP3 on waves 4-7) ----
  uint32_t ka0,ka1;
  tf2x32(0u,(uint32_t)seedp[0],0u,0u,ka0,ka1);
  const bool m = flag ? (mb!=0) : (mw32!=0u);
  float g0=0,g1=0,g2=0,g3=0;
  if (!m){
    g0=gumbel_of(ka0,ka1,(uint32_t)(nw*KK+4*lane+0));
    g1=gumbel_of(ka0,ka1,(uint32_t)(nw*KK+4*lane+1));
    g2=gumbel_of(ka0,ka1,(uint32_t)(nw*KK+4*lane+2));
    g3=gumbel_of(ka0,ka1,(uint32_t)(nw*KK+4*lane+3));
  }
  __syncthreads();   // sgt/G ready; bufB (h1) dead -> sp overlay OK

  // ---- VQ scores via mfma: 2 ct/wave ----
  {
    const int ct0 = wv*2, ct1 = ct0+1;
    const size_t term = (size_t)16*2*512;
    f32x4 s00={0.f,0.f,0.f,0.f}, s01=s00, s10=s00, s11=s00;
    const int ar = (lr&7)*SG + lg*8;
    #pragma unroll
    for (int s=0; s<2; ++s){
      const unsigned short* q0 = &pws[OCT + ((size_t)ct0*2 + s)*512 + (size_t)lane*8];
      const unsigned short* q1 = &pws[OCT + ((size_t)ct1*2 + s)*512 + (size_t)lane*8];
      short8 bh0=*(const short8*)q0, bm0=*(const short8*)(q0+term), bl0=*(const short8*)(q0+2*term);
      short8 bh1=*(const short8*)q1, bm1=*(const short8*)(q1+term), bl1=*(const short8*)(q1+2*term);
      short8 ah = *(const short8*)&Gh[ar + s*32];
      short8 am = *(const short8*)&Gm[ar + s*32];
      short8 al = *(const short8*)&Gl[ar + s*32];
      s00=MFMA(ah,bh0,s00,0,0,0); s01=MFMA(ah,bm0,s01,0,0,0);
      s00=MFMA(am,bh0,s00,0,0,0); s01=MFMA(am,bm0,s01,0,0,0);
      s00=MFMA(al,bh0,s00,0,0,0); s01=MFMA(ah,bl0,s01,0,0,0);
      s10=MFMA(ah,bh1,s10,0,0,0); s11=MFMA(ah,bm1,s11,0,0,0);
      s10=MFMA(am,bh1,s10,0,0,0); s11=MFMA(am,bm1,s11,0,0,0);
      s10=MFMA(al,bh1,s10,0,0,0); s11=MFMA(ah,bl1,s11,0,0,0);
    }
    const float cn0 = cnormp[ct0*16+lr], cn1 = cnormp[ct1*16+lr];
    if (lg < 2){
      #pragma unroll
      for (int j=0;j<4;++j){
        const int r = lg*4 + j;
        sp[r*SSP + ct0*16+lr] = cn0 - 2.f*(s00[j]+s01[j]);
        sp[r*SSP + ct1*16+lr] = cn1 - 2.f*(s10[j]+s11[j]);
      }
    }
  }
  __syncthreads();

  // ---- wave-local finalize: wave wv owns row nw ----
  {
    const int n = nw, r = wv;
    const float FMX = 3.402823466e38f;
    float4 dq = *(const float4*)&sp[r*SSP + 4*lane];
    float dv=dq.x; int di=4*lane;
    if (dq.y<dv){dv=dq.y;di=4*lane+1;}
    if (dq.z<dv){dv=dq.z;di=4*lane+2;}
    if (dq.w<dv){dv=dq.w;di=4*lane+3;}
    #pragma unroll
    for (int mm=32;mm;mm>>=1){
      float ov=__shfl_xor(dv,mm,64); int oi=__shfl_xor(di,mm,64);
      if (ov<dv||(ov==dv&&oi<di)){dv=ov;di=oi;}
    }
    const int i1=di;
    float v0=(4*lane+0==i1)?FMX:dq.x, v1=(4*lane+1==i1)?FMX:dq.y;
    float v2=(4*lane+2==i1)?FMX:dq.z, v3=(4*lane+3==i1)?FMX:dq.w;
    float ev=v0; int ei=4*lane;
    if (v1<ev){ev=v1;ei=4*lane+1;}
    if (v2<ev){ev=v2;ei=4*lane+2;}
    if (v3<ev){ev=v3;ei=4*lane+3;}
    #pragma unroll
    for (int mm=32;mm;mm>>=1){
      float ov=__shfl_xor(ev,mm,64); int oi=__shfl_xor(ei,mm,64);
      if (ov<ev||(ov==ev&&oi<ei)){ev=ov;ei=oi;}
    }
    const int i2=ei;
    // exact fp32 recheck of top-2
    const float gd = sgt[r*SSG + lane];
    float e1 = gd - Cg[(size_t)i1*DD + lane];
    float e2 = gd - Cg[(size_t)i2*DD + lane];
    float s1 = e1*e1, s2 = e2*e2;
    #pragma unroll
    for (int mm=32;mm;mm>>=1){ s1 += __shfl_xor(s1,mm,64); s2 += __shfl_xor(s2,mm,64); }
    const float D1 = sqrtf(s1), D2 = sqrtf(s2);
    const int qk = (D2<D1 || (D2==D1 && i2<i1)) ? i2 : i1;

    // prior normalization
    float s=((trq.x+trq.y)+trq.z)+trq.w;
    #pragma unroll
    for (int mm=32;mm;mm>>=1) s+=__shfl_xor(s,mm,64);
    float q0=trq.x/s, q1=trq.y/s, q2=trq.z/s, q3=trq.w/s;
    { bool f0=isfinite(ksq.x),f1=isfinite(ksq.y),f2=isfinite(ksq.z),f3=isfinite(ksq.w);
      if (__any(!(f0&&f1&&f2&&f3))){
        float4 sq=((const float4*)spk)[(size_t)n*(KK/4)+lane];
        if(!f0)q0=sq.x; if(!f1)q1=sq.y; if(!f2)q2=sq.z; if(!f3)q3=sq.w;
      } }
    const float lp0=logf(q0), lp1=logf(q1), lp2=logf(q2), lp3=logf(q3);
    const int jq=qk&3;
    float lps=(jq==0)?lp0:((jq==1)?lp1:((jq==2)?lp2:lp3));
    const float logqk=__shfl(lps,qk>>2,64);

    int sel;
    if (m){ sel=qk; }
    else {
      float sc=g0+lp0; int si=4*lane;
      { float g=g1+lp1; if(g>sc){sc=g;si=4*lane+1;} }
      { float g=g2+lp2; if(g>sc){sc=g;si=4*lane+2;} }
      { float g=g3+lp3; if(g>sc){sc=g;si=4*lane+3;} }
      #pragma unroll
      for (int mm=32;mm;mm>>=1){
        float ov=__shfl_xor(sc,mm,64); int oi=__shfl_xor(si,mm,64);
        if (ov>sc||(ov==sc&&oi<si)){sc=ov;si=oi;}
      }
      sel=si;
    }

    ((float4*)out_qk)[(size_t)n*(KK/4)+lane]=make_float4(
      (4*lane+0==qk)?1.f:0.f,(4*lane+1==qk)?1.f:0.f,
      (4*lane+2==qk)?1.f:0.f,(4*lane+3==qk)?1.f:0.f);

    const float c=Cg[(size_t)sel*DD+lane];
    out_z[(size_t)n*DD+lane]=c;
    float df = sgt[r*SSG + lane] - c;
    float p=df*df;
    #pragma unroll
    for (int mm=32;mm;mm>>=1) p+=__shfl_xor(p,mm,64);
    if (lane==0){
      float tt=sqrtf(p);
      float dkl=-logqk;
      out_kl[n]=(tt+0.25f*tt)+dkl;
      out_dkl[n]=dkl;
    }
  }
}

extern "C" void kernel_launch(void* const* d_in, const int* in_sizes, int n_in,
                              void* d_out, int out_size, void* d_ws, size_t ws_size,
                              hipStream_t stream){
  const float* z    = (const float*)d_in[1];
  const float* ksm  = (const float*)d_in[2];
  const float* xt   = (const float*)d_in[3];
  const void*  mask = d_in[4];
  const float* tr   = (const float*)d_in[5];
  const float* spk  = (const float*)d_in[6];
  const float* W1   = (const float*)d_in[7];
  const float* b1   = (const float*)d_in[8];
  const float* W2   = (const float*)d_in[9];
  const float* b2   = (const float*)d_in[10];
  const float* W3   = (const float*)d_in[11];
  const float* b3   = (const float*)d_in[12];
  const float* C    = (const float*)d_in[13];
  const int*   seed = (const int*)d_in[14];

  float* out_z   = (float*)d_out;                // N*D
  float* out_kl  = out_z   + (size_t)NN*DD;      // N
  float* out_dkl = out_kl  + NN;                 // N
  float* out_qk  = out_dkl + NN;                 // N*K

  unsigned short* ws = (unsigned short*)d_ws;
  k_prep<<<73,256,0,stream>>>(W1, W2, W3, C, ws);
  k_fused<<<GRID,NT,0,stream>>>(z, ksm, xt, mask, tr, spk,
                                b1, b2, b3, C, seed, ws,
                                out_z, out_kl, out_dkl, out_qk);
}

// Round 18
// 28.679 us; speedup vs baseline: 1.3636x; 1.3636x over previous
//
#include <hip/hip_runtime.h>
#include <cstdint>
#include <cmath>

#define NN   4096
#define DXX  128
#define DD   64
#define KK   256
#define HH   256
#define DIN  192
#define ROWS 16
#define NT   1024
#define GRID (NN/ROWS)   // 256 blocks, 1 per CU, 16 waves -> 4 waves/SIMD

typedef __attribute__((ext_vector_type(8))) short short8;
typedef __attribute__((ext_vector_type(4))) float f32x4;
#define MFMA __builtin_amdgcn_mfma_f32_16x16x32_bf16

// ---- packed-weight offsets in d_ws (ushort units); 2-term (h,m) split ----
#define OW1 0          // 2 terms x 16ct x 6ks x 512 = 98304
#define OW2 98304      // 2 x 16 x 8 x 512 = 131072
#define OW3 229376     // 2 x 4  x 8 x 512 = 32768
#define OCT 262144     // 2 x 16 x 2 x 512 = 32768
#define OCN 294912     // 256 f32 (codebook row norms)

// ---- LDS strides ----
#define SW  264        // act row stride (ushorts)
#define SG  72         // gt-split row stride (ushorts)
#define SSP 260        // score row stride (floats)
#define SSG 68         // sgt row stride (floats)

__device__ __forceinline__ unsigned short f2bf(float x){
  uint32_t u = __float_as_uint(x);
  return (unsigned short)((u + 0x7fffu + ((u>>16)&1u)) >> 16);
}
__device__ __forceinline__ float bf2f(unsigned short b){
  return __uint_as_float(((uint32_t)b)<<16);
}
__device__ __forceinline__ void split2(float x, unsigned short& h, unsigned short& m){
  h = f2bf(x); float r1 = x - bf2f(h);
  m = f2bf(r1);                       // h+m captures ~17 mantissa bits
}

// ---------------- Threefry-2x32 (20 rounds), exact JAX semantics ----------------
__device__ __forceinline__ uint32_t rotl32(uint32_t v, uint32_t r){ return (v<<r)|(v>>(32u-r)); }
__device__ __forceinline__ void tf2x32(uint32_t k0, uint32_t k1,
                                       uint32_t x0, uint32_t x1,
                                       uint32_t& o0, uint32_t& o1){
  const uint32_t ks0=k0, ks1=k1, ks2 = k0 ^ k1 ^ 0x1BD11BDAu;
  x0 += ks0; x1 += ks1;
  x0+=x1; x1=rotl32(x1,13); x1^=x0;
  x0+=x1; x1=rotl32(x1,15); x1^=x0;
  x0+=x1; x1=rotl32(x1,26); x1^=x0;
  x0+=x1; x1=rotl32(x1, 6); x1^=x0;
  x0+=ks1; x1+=ks2+1u;
  x0+=x1; x1=rotl32(x1,17); x1^=x0;
  x0+=x1; x1=rotl32(x1,29); x1^=x0;
  x0+=x1; x1=rotl32(x1,16); x1^=x0;
  x0+=x1; x1=rotl32(x1,24); x1^=x0;
  x0+=ks2; x1+=ks0+2u;
  x0+=x1; x1=rotl32(x1,13); x1^=x0;
  x0+=x1; x1=rotl32(x1,15); x1^=x0;
  x0+=x1; x1=rotl32(x1,26); x1^=x0;
  x0+=x1; x1=rotl32(x1, 6); x1^=x0;
  x0+=ks0; x1+=ks1+3u;
  x0+=x1; x1=rotl32(x1,17); x1^=x0;
  x0+=x1; x1=rotl32(x1,29); x1^=x0;
  x0+=x1; x1=rotl32(x1,16); x1^=x0;
  x0+=x1; x1=rotl32(x1,24); x1^=x0;
  x0+=ks1; x1+=ks2+4u;
  x0+=x1; x1=rotl32(x1,13); x1^=x0;
  x0+=x1; x1=rotl32(x1,15); x1^=x0;
  x0+=x1; x1=rotl32(x1,26); x1^=x0;
  x0+=x1; x1=rotl32(x1, 6); x1^=x0;
  x0+=ks2; x1+=ks0+5u;
  o0=x0; o1=x1;
}
__device__ __forceinline__ float gumbel_of(uint32_t ka0, uint32_t ka1, uint32_t idx){
  uint32_t o0,o1; tf2x32(ka0,ka1,0u,idx,o0,o1);
  const uint32_t bits = o0 ^ o1;
  const float TINY = 1.17549435e-38f;
  const float f = __uint_as_float((bits>>9) | 0x3F800000u) - 1.0f;
  const float u = fmaxf(TINY, f + TINY);
  return -logf(-logf(u));
}

// ---------------- prep: coalesced loads -> LDS transpose -> short8 stores (2-term) ----
// blocks: 0-5 W1(ks), 6-13 W2(ks), 14-21 W3(ks), 22-23 Cg^T(ks), 24 norms
__global__ __launch_bounds__(256) void k_prep(const float* __restrict__ W1,
    const float* __restrict__ W2, const float* __restrict__ W3,
    const float* __restrict__ Cg, unsigned short* __restrict__ ws){
  const int b = blockIdx.x, t = threadIdx.x;
  __shared__ __align__(16) float lds[8960];   // max: CT 256*35; W: 32*261
  if (b < 22){
    const float* W; int N, KS, NTt; size_t base; int ks;
    if (b < 6){ W=W1; N=256; KS=6; NTt=16; base=OW1; ks=b; }
    else if (b < 14){ W=W2; N=256; KS=8; NTt=16; base=OW2; ks=b-6; }
    else { W=W3; N=64; KS=8; NTt=4; base=OW3; ks=b-14; }
    const int k0 = ks*32;
    const int nf4 = 32*(N/4);
    const int LDW = 261;
    for (int idx=t; idx<nf4; idx+=256){
      int row = idx/(N/4), c4 = idx%(N/4);
      float4 v = *(const float4*)&W[(size_t)(k0+row)*N + c4*4];
      float* d = &lds[row*LDW + c4*4];
      d[0]=v.x; d[1]=v.y; d[2]=v.z; d[3]=v.w;
    }
    __syncthreads();
    const size_t term = (size_t)NTt*KS*512;
    const int nslots = NTt*64;
    for (int slot=t; slot<nslots; slot+=256){
      const int lane = slot&63, ct = slot>>6;
      const int c = ct*16 + (lane&15);
      const int kofs = 8*(lane>>4);
      short8 hv,mv;
      #pragma unroll
      for (int j=0;j<8;++j){
        float w = lds[(kofs+j)*LDW + c];
        unsigned short h,m; split2(w,h,m);
        hv[j]=(short)h; mv[j]=(short)m;
      }
      const size_t o = base + ((size_t)ct*KS+ks)*512 + (size_t)lane*8;
      *(short8*)&ws[o]=hv; *(short8*)&ws[o+term]=mv;
    }
  } else if (b < 24){
    const int ks = b-22, d0 = ks*32;
    const int LDC = 35;
    for (int idx=t; idx<2048; idx+=256){      // 256 codes x 8 float4 (32 d-cols)
      int code = idx>>3, d4 = idx&7;
      float4 v = *(const float4*)&Cg[(size_t)code*64 + d0 + d4*4];
      float* d = &lds[code*LDC + d4*4];
      d[0]=v.x; d[1]=v.y; d[2]=v.z; d[3]=v.w;
    }
    __syncthreads();
    const size_t term = (size_t)16*2*512;
    for (int slot=t; slot<1024; slot+=256){
      const int lane = slot&63, ct = slot>>6;
      const int c = ct*16 + (lane&15);
      const int kofs = 8*(lane>>4);
      short8 hv,mv;
      #pragma unroll
      for (int j=0;j<8;++j){
        float w = lds[c*LDC + kofs + j];
        unsigned short h,m; split2(w,h,m);
        hv[j]=(short)h; mv[j]=(short)m;
      }
      const size_t o = OCT + ((size_t)ct*2+ks)*512 + (size_t)lane*8;
      *(short8*)&ws[o]=hv; *(short8*)&ws[o+term]=mv;
    }
  } else {
    const int c = t;
    float s=0.f;
    #pragma unroll 8
    for (int d=0; d<64; ++d){ float v=Cg[(size_t)c*64+d]; s += v*v; }
    ((float*)(ws+OCN))[c] = s;
  }
}

// ---------------- fused main kernel: 16 waves, 1 ct/wave, 2-term split ----------------
__global__ __launch_bounds__(NT,4) void k_fused(
    const float* __restrict__ z, const float* __restrict__ ks,
    const float* __restrict__ xt, const void* __restrict__ maskp,
    const float* __restrict__ tr, const float* __restrict__ spk,
    const float* __restrict__ b1, const float* __restrict__ b2,
    const float* __restrict__ b3, const float* __restrict__ Cg,
    const int* __restrict__ seedp, const unsigned short* __restrict__ pws,
    float* __restrict__ out_z, float* __restrict__ out_kl,
    float* __restrict__ out_dkl, float* __restrict__ out_qk)
{
  const int t    = threadIdx.x;
  const int lane = t & 63;
  const int wv   = t >> 6;            // wave 0..15
  const int lr   = lane & 15;
  const int lg   = lane >> 4;
  const int n0   = blockIdx.x * ROWS;
  const int nw   = n0 + wv;           // finalize: wave wv owns row nw

  // LDS (bytes): bufA 2x16xSW [0,16896) | bufB 2x16xSW [16896,33792) (sp overlay 16640)
  //              sgt 16xSSG [33792,38144) | G 2x16xSG [38144,42752)
  __shared__ __align__(16) char smem[42752];
  unsigned short* Ah = (unsigned short*)smem;            // bufA: layer input / h2
  unsigned short* Am = Ah + 16*SW;
  unsigned short* Bh = (unsigned short*)(smem + 16896);  // bufB: h1 (later sp overlay)
  unsigned short* Bm = Bh + 16*SW;
  float* sp  = (float*)(smem + 16896);
  float* sgt = (float*)(smem + 33792);
  unsigned short* Gh = (unsigned short*)(smem + 38144);
  unsigned short* Gm = Gh + 16*SG;
  __shared__ int sh_flag;
  const float* cnormp = (const float*)(pws + OCN);

  // ---- early long-latency loads (hidden under MLP) ----
  const float4 ksq = ((const float4*)ks)[(size_t)nw*(KK/4)+lane];
  int kv=0x7fffffff;
  if (isfinite(ksq.x)&&ksq.x>0.5f) kv=4*lane+0;
  if (isfinite(ksq.y)&&ksq.y>0.5f&&4*lane+1<kv) kv=4*lane+1;
  if (isfinite(ksq.z)&&ksq.z>0.5f&&4*lane+2<kv) kv=4*lane+2;
  if (isfinite(ksq.w)&&ksq.w>0.5f&&4*lane+3<kv) kv=4*lane+3;
  { unsigned long long bl=__ballot(kv!=0x7fffffff);
    if (bl){ int src=(int)__builtin_ctzll(bl); kv=__shfl(kv,src,64); } else kv=0; }
  const int kidx = kv;
  const float4 trq = ((const float4*)tr)[(size_t)nw*(KK*KK/4)+(size_t)kidx*(KK/4)+lane];
  const unsigned char mb = ((const unsigned char*)maskp)[nw];
  const uint32_t      mw32 = ((const uint32_t*)maskp)[nw];

  if (t==0) sh_flag = 0;
  __syncthreads();
  {
    const uint32_t* mwp = (const uint32_t*)maskp;
    uint32_t wd = mwp[t];
    if (wd!=0u && wd!=1u && wd!=0x3F800000u) atomicOr(&sh_flag,1);
  }

  // ---- stage layer-1 input with 2-term split ----
  for (int i=t; i<ROWS*DIN; i+=NT){
    int r=i/DIN, d=i%DIN; float v;
    if (d<DD){ v = z[(size_t)(n0+r)*DD+d]; if(!isfinite(v)) v=0.f; }
    else     { v = xt[(size_t)(n0+r)*DXX + (d-DD)]; }
    unsigned short h,m; split2(v,h,m);
    Ah[r*SW+d]=h; Am[r*SW+d]=m;
  }
  __syncthreads();
  const int flag = sh_flag;

  // ---- mfma GEMM layer (1 ct/wave), 4 MFMAs/step, depth-1 weight prefetch ----
  auto gemm_layer = [&](const unsigned short* Xh, const unsigned short* Xm,
                        int KS, size_t wbase, const float* bias,
                        unsigned short* Yh, unsigned short* Ym){
    const int ct = wv;
    const size_t term = (size_t)16*KS*512;
    const float bb = bias[ct*16+lr];
    f32x4 a0 = {bb,bb,bb,bb}, a1 = {0.f,0.f,0.f,0.f};
    const int ar = lr*SW + lg*8;
    const unsigned short* p = &pws[wbase + ((size_t)ct*KS)*512 + (size_t)lane*8];
    short8 bh = *(const short8*)p, bm = *(const short8*)(p+term);
    #pragma unroll 1
    for (int s=0; s<KS; ++s){
      short8 nbh, nbm;
      if (s+1<KS){
        const unsigned short* q = p + (size_t)(s+1)*512;
        nbh=*(const short8*)q; nbm=*(const short8*)(q+term);
      }
      short8 ah = *(const short8*)&Xh[ar + s*32];
      short8 am = *(const short8*)&Xm[ar + s*32];
      a0=MFMA(ah,bh,a0,0,0,0); a1=MFMA(ah,bm,a1,0,0,0);
      a0=MFMA(am,bh,a0,0,0,0); a1=MFMA(am,bm,a1,0,0,0);
      bh=nbh; bm=nbm;
    }
    #pragma unroll
    for (int j=0;j<4;++j){
      const int r = lg*4 + j;
      float h0 = tanhf(a0[j]+a1[j]);
      unsigned short hh,hm; split2(h0,hh,hm);
      Yh[r*SW + ct*16+lr]=hh; Ym[r*SW + ct*16+lr]=hm;
    }
  };

  gemm_layer(Ah,Am, 6, OW1, b1, Bh,Bm);   // h1 -> bufB
  __syncthreads();
  gemm_layer(Bh,Bm, 8, OW2, b2, Ah,Am);   // h2 -> bufA
  __syncthreads();

  // ---- MLP3: gt = h2 @ W3 + b3 (waves 0-3, one 16-col tile each) ----
  if (wv < 4){
    const int ct = wv;
    const size_t term = (size_t)4*8*512;
    const float bb = b3[ct*16+lr];
    f32x4 a0 = {bb,bb,bb,bb}, a1 = {0.f,0.f,0.f,0.f};
    const int ar = lr*SW + lg*8;
    const unsigned short* p = &pws[OW3 + ((size_t)ct*8)*512 + (size_t)lane*8];
    short8 bh = *(const short8*)p, bm = *(const short8*)(p+term);
    #pragma unroll 1
    for (int s=0; s<8; ++s){
      short8 nbh, nbm;
      if (s+1<8){
        const unsigned short* q = p + (size_t)(s+1)*512;
        nbh=*(const short8*)q; nbm=*(const short8*)(q+term);
      }
      short8 ah = *(const short8*)&Ah[ar + s*32];
      short8 am = *(const short8*)&Am[ar + s*32];
      a0=MFMA(ah,bh,a0,0,0,0); a1=MFMA(ah,bm,a1,0,0,0);
      a0=MFMA(am,bh,a0,0,0,0); a1=MFMA(am,bm,a1,0,0,0);
      bh=nbh; bm=nbm;
    }
    #pragma unroll
    for (int j=0;j<4;++j){
      const int r = lg*4 + j;
      float g = a0[j]+a1[j];
      sgt[r*SSG + ct*16+lr] = g;
      unsigned short gh,gm; split2(g,gh,gm);
      Gh[r*SG + ct*16+lr]=gh; Gm[r*SG + ct*16+lr]=gm;
    }
  }

  // ---- gumbel precompute (VALU, overlaps MLP3 on waves 4-15) ----
  uint32_t ka0,ka1;
  tf2x32(0u,(uint32_t)seedp[0],0u,0u,ka0,ka1);
  const bool m = flag ? (mb!=0) : (mw32!=0u);
  float g0=0,g1=0,g2=0,g3=0;
  if (!m){
    g0=gumbel_of(ka0,ka1,(uint32_t)(nw*KK+4*lane+0));
    g1=gumbel_of(ka0,ka1,(uint32_t)(nw*KK+4*lane+1));
    g2=gumbel_of(ka0,ka1,(uint32_t)(nw*KK+4*lane+2));
    g3=gumbel_of(ka0,ka1,(uint32_t)(nw*KK+4*lane+3));
  }
  __syncthreads();   // sgt/G ready; bufB (h1) dead -> sp overlay OK

  // ---- VQ scores via mfma: score[r][c] = ||C_c||^2 - 2 * (gt . C_c) ----
  {
    const int ct = wv;
    const size_t term = (size_t)16*2*512;
    f32x4 s0={0.f,0.f,0.f,0.f}, s1=s0;
    const int ar = lr*SG + lg*8;
    #pragma unroll
    for (int s=0; s<2; ++s){
      short8 ah = *(const short8*)&Gh[ar + s*32];
      short8 am = *(const short8*)&Gm[ar + s*32];
      const unsigned short* p = &pws[OCT + ((size_t)ct*2 + s)*512 + (size_t)lane*8];
      short8 bh=*(const short8*)p, bm=*(const short8*)(p+term);
      s0=MFMA(ah,bh,s0,0,0,0); s1=MFMA(ah,bm,s1,0,0,0);
      s0=MFMA(am,bh,s0,0,0,0); s1=MFMA(am,bm,s1,0,0,0);
    }
    const float cn = cnormp[ct*16+lr];
    #pragma unroll
    for (int j=0;j<4;++j){
      const int r = lg*4 + j;
      sp[r*SSP + ct*16+lr] = cn - 2.f*(s0[j]+s1[j]);
    }
  }
  __syncthreads();

  // ---- wave-local finalize: wave wv owns row nw ----
  {
    const int n = nw, r = wv;
    const float FMX = 3.402823466e38f;
    float4 dq = *(const float4*)&sp[r*SSP + 4*lane];
    float dv=dq.x; int di=4*lane;
    if (dq.y<dv){dv=dq.y;di=4*lane+1;}
    if (dq.z<dv){dv=dq.z;di=4*lane+2;}
    if (dq.w<dv){dv=dq.w;di=4*lane+3;}
    #pragma unroll
    for (int mm=32;mm;mm>>=1){
      float ov=__shfl_xor(dv,mm,64); int oi=__shfl_xor(di,mm,64);
      if (ov<dv||(ov==dv&&oi<di)){dv=ov;di=oi;}
    }
    const int i1=di;
    float v0=(4*lane+0==i1)?FMX:dq.x, v1=(4*lane+1==i1)?FMX:dq.y;
    float v2=(4*lane+2==i1)?FMX:dq.z, v3=(4*lane+3==i1)?FMX:dq.w;
    float ev=v0; int ei=4*lane;
    if (v1<ev){ev=v1;ei=4*lane+1;}
    if (v2<ev){ev=v2;ei=4*lane+2;}
    if (v3<ev){ev=v3;ei=4*lane+3;}
    #pragma unroll
    for (int mm=32;mm;mm>>=1){
      float ov=__shfl_xor(ev,mm,64); int oi=__shfl_xor(ei,mm,64);
      if (ov<ev||(ov==ev&&oi<ei)){ev=ov;ei=oi;}
    }
    const int i2=ei;
    // exact fp32 recheck of top-2 (selection bit-exactness)
    const float gd = sgt[r*SSG + lane];
    float e1 = gd - Cg[(size_t)i1*DD + lane];
    float e2 = gd - Cg[(size_t)i2*DD + lane];
    float s1 = e1*e1, s2 = e2*e2;
    #pragma unroll
    for (int mm=32;mm;mm>>=1){ s1 += __shfl_xor(s1,mm,64); s2 += __shfl_xor(s2,mm,64); }
    const float D1 = sqrtf(s1), D2 = sqrtf(s2);
    const int qk = (D2<D1 || (D2==D1 && i2<i1)) ? i2 : i1;

    // prior normalization
    float s=((trq.x+trq.y)+trq.z)+trq.w;
    #pragma unroll
    for (int mm=32;mm;mm>>=1) s+=__shfl_xor(s,mm,64);
    float q0=trq.x/s, q1=trq.y/s, q2=trq.z/s, q3=trq.w/s;
    { bool f0=isfinite(ksq.x),f1=isfinite(ksq.y),f2=isfinite(ksq.z),f3=isfinite(ksq.w);
      if (__any(!(f0&&f1&&f2&&f3))){
        float4 sq=((const float4*)spk)[(size_t)n*(KK/4)+lane];
        if(!f0)q0=sq.x; if(!f1)q1=sq.y; if(!f2)q2=sq.z; if(!f3)q3=sq.w;
      } }
    const float lp0=logf(q0), lp1=logf(q1), lp2=logf(q2), lp3=logf(q3);
    const int jq=qk&3;
    float lps=(jq==0)?lp0:((jq==1)?lp1:((jq==2)?lp2:lp3));
    const float logqk=__shfl(lps,qk>>2,64);

    int sel;
    if (m){ sel=qk; }
    else {
      float sc=g0+lp0; int si=4*lane;
      { float g=g1+lp1; if(g>sc){sc=g;si=4*lane+1;} }
      { float g=g2+lp2; if(g>sc){sc=g;si=4*lane+2;} }
      { float g=g3+lp3; if(g>sc){sc=g;si=4*lane+3;} }
      #pragma unroll
      for (int mm=32;mm;mm>>=1){
        float ov=__shfl_xor(sc,mm,64); int oi=__shfl_xor(si,mm,64);
        if (ov>sc||(ov==sc&&oi<si)){sc=ov;si=oi;}
      }
      sel=si;
    }

    ((float4*)out_qk)[(size_t)n*(KK/4)+lane]=make_float4(
      (4*lane+0==qk)?1.f:0.f,(4*lane+1==qk)?1.f:0.f,
      (4*lane+2==qk)?1.f:0.f,(4*lane+3==qk)?1.f:0.f);

    const float c=Cg[(size_t)sel*DD+lane];
    out_z[(size_t)n*DD+lane]=c;
    float df = sgt[r*SSG + lane] - c;
    float p=df*df;
    #pragma unroll
    for (int mm=32;mm;mm>>=1) p+=__shfl_xor(p,mm,64);
    if (lane==0){
      float tt=sqrtf(p);
      float dkl=-logqk;
      out_kl[n]=(tt+0.25f*tt)+dkl;
      out_dkl[n]=dkl;
    }
  }
}

extern "C" void kernel_launch(void* const* d_in, const int* in_sizes, int n_in,
                              void* d_out, int out_size, void* d_ws, size_t ws_size,
                              hipStream_t stream){
  const float* z    = (const float*)d_in[1];
  const float* ksm  = (const float*)d_in[2];
  const float* xt   = (const float*)d_in[3];
  const void*  mask = d_in[4];
  const float* tr   = (const float*)d_in[5];
  const float* spk  = (const float*)d_in[6];
  const float* W1   = (const float*)d_in[7];
  const float* b1   = (const float*)d_in[8];
  const float* W2   = (const float*)d_in[9];
  const float* b2   = (const float*)d_in[10];
  const float* W3   = (const float*)d_in[11];
  const float* b3   = (const float*)d_in[12];
  const float* C    = (const float*)d_in[13];
  const int*   seed = (const int*)d_in[14];

  float* out_z   = (float*)d_out;                // N*D
  float* out_kl  = out_z   + (size_t)NN*DD;      // N
  float* out_dkl = out_kl  + NN;                 // N
  float* out_qk  = out_dkl + NN;                 // N*K

  unsigned short* ws = (unsigned short*)d_ws;
  k_prep<<<25,256,0,stream>>>(W1, W2, W3, C, ws);
  k_fused<<<GRID,NT,0,stream>>>(z, ksm, xt, mask, tr, spk,
                                b1, b2, b3, C, seed, ws,
                                out_z, out_kl, out_dkl, out_qk);
}